// Round 4
// baseline (127.040 us; speedup 1.0000x reference)
//
#include <hip/hip_runtime.h>

#define Tcnt 32768      // B*S
#define Gn   2
#define Vn   320
#define Dn   128
#define DIMK 512
#define GV   640        // G*V

typedef __attribute__((ext_vector_type(8))) short bf16x8;
typedef __attribute__((ext_vector_type(8))) ushort u16x8;
typedef __attribute__((ext_vector_type(4))) float f32x4;

__device__ inline ushort f2bf(float x) {
    unsigned u = __float_as_uint(x);
    return (ushort)((u + 0x7fffu + ((u >> 16) & 1u)) >> 16);   // RNE
}

#define AS1(p) ((const __attribute__((address_space(1))) void*)(p))
#define AS3(p) ((__attribute__((address_space(3))) void*)(p))

// ---------------- prep: W [512,640] fp32 -> Wt [640,512] bf16 (transposed) ----------
__global__ __launch_bounds__(256) void prep_wt(
    const float* __restrict__ W, ushort* __restrict__ Wt)
{
    __shared__ ushort Ls[64][72];
    int t = blockIdx.x;                     // 0..79
    int n0 = (t % 10) * 64, k0 = (t / 10) * 64;
    int ln = threadIdx.x & 63, kq = threadIdx.x >> 6;
    #pragma unroll
    for (int kk = 0; kk < 16; ++kk) {
        int k = kq * 16 + kk;
        Ls[k][ln] = f2bf(W[(size_t)(k0 + k) * GV + n0 + ln]);
    }
    __syncthreads();
    #pragma unroll
    for (int nn = 0; nn < 16; ++nn) {
        int n = kq * 16 + nn;
        Wt[(size_t)(n0 + n) * DIMK + k0 + ln] = Ls[ln][n];
    }
}

// ---------------- fused: GEMM(BMx640) + bias + softmax + gumbel-argmax(+fixup) + gather
__global__ __launch_bounds__(512, 2) void fused_vq_kernel(
    const float*  __restrict__ hs,    // [T, 512] fp32
    const ushort* __restrict__ Wt,    // [640, 512] bf16 transposed
    const float*  __restrict__ W,     // [512, 640] fp32 (fixup only)
    const float*  __restrict__ bias,  // [640]
    const float*  __restrict__ gum,   // [T*G, 320]
    const float*  __restrict__ cv,    // [640, 128]
    float* __restrict__ out,          // [T, 256]
    float* __restrict__ dist)         // [T*G, 320]
{
    __shared__ ushort Bs[2][GV * 32];     // 80 KB, chunk-swizzled [n][cp][8]
    __shared__ ushort As[2][128 * 32];    // 16 KB, chunk-swizzled [m][cp][8]
    __shared__ int   s_cnt[8][32];
    __shared__ int   s_bidx[8][32];
    __shared__ int   s_ccol[8][32][8];
    __shared__ float s_cgum[8][32][8];

    const int tid = threadIdx.x, w = tid >> 6, lane = tid & 63;
    const int Q = lane >> 4, c16 = lane & 15;
    const size_t t0 = (size_t)blockIdx.x * 128;

    if (lane < 32) s_cnt[w][lane] = 0;

    // A staging mapping: slot tid -> (m, phys chunk); source pre-swizzled (rule 21)
    const int am = tid >> 2, acp = tid & 3, acl = acp ^ (am & 3);
    const float* asrc = hs + (t0 + am) * DIMK + acl * 8;

    auto stageA = [&](int buf, int k0) {
        float4 x = *(const float4*)(asrc + k0);
        float4 y = *(const float4*)(asrc + k0 + 4);
        u16x8 o;
        o[0]=f2bf(x.x); o[1]=f2bf(x.y); o[2]=f2bf(x.z); o[3]=f2bf(x.w);
        o[4]=f2bf(y.x); o[5]=f2bf(y.y); o[6]=f2bf(y.z); o[7]=f2bf(y.w);
        *(u16x8*)&As[buf][tid * 8] = o;
    };
    auto stageB = [&](int buf, int k0) {
        #pragma unroll
        for (int i = 0; i < 5; ++i) {
            int s = i * 512 + tid;
            int n = s >> 2, cp = s & 3, cl = cp ^ (n & 3);
            __builtin_amdgcn_global_load_lds(
                AS1(Wt + (size_t)n * DIMK + k0 + cl * 8),
                AS3(&Bs[buf][s * 8]), 16, 0, 0);
        }
    };

    stageA(0, 0); stageB(0, 0);
    __syncthreads();

    f32x4 acc[40];
    #pragma unroll
    for (int f = 0; f < 40; ++f) acc[f] = (f32x4){0.f, 0.f, 0.f, 0.f};

    const int arow = w * 16 + c16;
    const int aoff = (arow * 4 + (Q ^ (arow & 3))) * 8;

    int cur = 0;
    for (int ks = 0; ks < 16; ++ks) {
        if (ks < 15) { stageA(cur ^ 1, (ks + 1) * 32); stageB(cur ^ 1, (ks + 1) * 32); }
        bf16x8 af = *(const bf16x8*)&As[cur][aoff];
        #pragma unroll
        for (int f = 0; f < 40; ++f) {
            int n = f * 16 + c16;
            bf16x8 bv = *(const bf16x8*)&Bs[cur][(n * 4 + (Q ^ (n & 3))) * 8];
            acc[f] = __builtin_amdgcn_mfma_f32_16x16x32_bf16(af, bv, acc[f], 0, 0, 0);
        }
        __syncthreads();
        cur ^= 1;
    }

    // ---- bias into acc (C/D layout: row = Q*4+q, col = f*16+c16) ----
    #pragma unroll
    for (int f = 0; f < 40; ++f) {
        float bb = bias[f * 16 + c16];
        acc[f][0] += bb; acc[f][1] += bb; acc[f][2] += bb; acc[f][3] += bb;
    }

    const float MARGIN = 0.0625f;

    // ---- per-row (4 per lane), per-group: softmax -> dist, gumbel argmax + candidates
    #pragma unroll
    for (int q = 0; q < 4; ++q) {
        int rl = Q * 4 + q;
        size_t t = t0 + w * 16 + rl;
        #pragma unroll
        for (int g = 0; g < 2; ++g) {
            size_t r2 = t * 2 + g;
            const float* gr = gum + r2 * Vn;
            float s[20];
            float mxl = -1e30f, mxs = -1e30f; int bi = 0;
            #pragma unroll
            for (int j = 0; j < 20; ++j) {
                float lb = acc[g * 20 + j][q];
                float gv = gr[j * 16 + c16];
                float sc = lb + gv; s[j] = sc;
                mxl = fmaxf(mxl, lb);
                if (sc > mxs) { mxs = sc; bi = j * 16 + c16; }
            }
            #pragma unroll
            for (int off = 1; off < 16; off <<= 1) {
                mxl = fmaxf(mxl, __shfl_xor(mxl, off));
                float os = __shfl_xor(mxs, off); int ob = __shfl_xor(bi, off);
                if (os > mxs || (os == mxs && ob < bi)) { mxs = os; bi = ob; }
            }
            float sum = 0.f;
            #pragma unroll
            for (int j = 0; j < 20; ++j) sum += __expf(acc[g * 20 + j][q] - mxl);
            #pragma unroll
            for (int off = 1; off < 16; off <<= 1) sum += __shfl_xor(sum, off);
            float inv = 1.0f / sum;
            float* dr = dist + r2 * Vn;
            #pragma unroll
            for (int j = 0; j < 20; ++j)
                dr[j * 16 + c16] = __expf(acc[g * 20 + j][q] - mxl) * inv;

            int unit = rl * 2 + g;
            if (c16 == 0) s_bidx[w][unit] = bi;
            float thr = mxs - MARGIN;
            int tot = 0;
            #pragma unroll
            for (int j = 0; j < 20; ++j) tot += (s[j] >= thr) ? 1 : 0;
            #pragma unroll
            for (int off = 1; off < 16; off <<= 1) tot += __shfl_xor(tot, off);
            if (tot > 1) {
                #pragma unroll
                for (int j = 0; j < 20; ++j) if (s[j] >= thr) {
                    int pos = atomicAdd(&s_cnt[w][unit], 1);
                    if (pos < 8) {
                        s_ccol[w][unit][pos] = j * 16 + c16;
                        s_cgum[w][unit][pos] = s[j] - acc[g * 20 + j][q];
                    }
                }
            }
        }
    }

    // ---- fixup: exact fp32 recompute for near-tie units (wave-uniform branch) ----
    for (int u = 0; u < 32; ++u) {
        int cnt = s_cnt[w][u];
        if (cnt < 2) continue;
        if (cnt > 8) cnt = 8;
        int rl = u >> 1, g = u & 1;
        size_t t = t0 + w * 16 + rl;
        const float* hr = hs + t * DIMK;
        float4 h0 = *(const float4*)(hr + lane * 8);
        float4 h1 = *(const float4*)(hr + lane * 8 + 4);
        float hv[8] = {h0.x, h0.y, h0.z, h0.w, h1.x, h1.y, h1.z, h1.w};
        float bb = -1e30f; int bv2 = 1 << 30;
        for (int j = 0; j < cnt; ++j) {
            int v = s_ccol[w][u][j]; float gvl = s_cgum[w][u][j];
            int gcol = g * Vn + v;
            const float* wc = W + gcol;
            float p = 0.f;
            #pragma unroll
            for (int i = 0; i < 8; ++i)
                p = fmaf(hv[i], wc[(size_t)(lane * 8 + i) * GV], p);
            #pragma unroll
            for (int off = 1; off < 64; off <<= 1) p += __shfl_xor(p, off);
            float se = p + bias[gcol] + gvl;
            if (se > bb || (se == bb && v < bv2)) { bb = se; bv2 = v; }
        }
        if (lane == 0) s_bidx[w][u] = bv2;
    }

    // ---- gather codevectors -> out (bit-exact copy) ----
    for (int u = 0; u < 32; ++u) {
        int rl = u >> 1, g = u & 1;
        size_t t = t0 + w * 16 + rl;
        int b = s_bidx[w][u];
        const float2* cvr = (const float2*)(cv + ((size_t)(g * Vn + b)) * Dn);
        float2 val = cvr[lane];
        *(float2*)(out + t * (Gn * Dn) + g * Dn + lane * 2) = val;
    }
}

extern "C" void kernel_launch(void* const* d_in, const int* in_sizes, int n_in,
                              void* d_out, int out_size, void* d_ws, size_t ws_size,
                              hipStream_t stream) {
    const float* hs  = (const float*)d_in[0];  // [8,4096,512]
    const float* W   = (const float*)d_in[1];  // [512,640]
    const float* b   = (const float*)d_in[2];  // [640]
    const float* cv  = (const float*)d_in[3];  // [640,128]
    const float* gum = (const float*)d_in[4];  // [65536,320]

    float* out  = (float*)d_out;                      // [32768, 256]
    float* dist = out + (size_t)Tcnt * (Gn * Dn);     // [65536, 320]
    ushort* Wt  = (ushort*)d_ws;                      // [640, 512] bf16 = 640 KB

    prep_wt<<<80, 256, 0, stream>>>(W, Wt);
    fused_vq_kernel<<<Tcnt / 128, 512, 0, stream>>>(hs, Wt, W, b, gum, cv, out, dist);
}